// Round 9
// baseline (527.031 us; speedup 1.0000x reference)
//
#include <hip/hip_runtime.h>
#include <hip/hip_bf16.h>
#include <stdint.h>

// Problem dims (fixed)
#define NB 8
#define NS 2048
#define ND 1024
#define NH 4096
#define NE 8
#define NTOK (NB*NS)   // 16384 tokens

typedef __bf16 bf16;
typedef bf16 bf16x8 __attribute__((ext_vector_type(8)));
typedef float f32x4 __attribute__((ext_vector_type(4)));

// ws layout: meta[512] ints + perm[16384] at meta+512, then:
static const size_t OFF_XB  = 128 * 1024;                          // (unused now, kept for layout stability)
static const size_t OFF_WTE = OFF_XB  + (size_t)NTOK * ND * 2;     // bf16 wte[NE][NH][ND]
static const size_t OFF_WTO = OFF_WTE + (size_t)NE * NH * ND * 2;  // bf16 wto[ND][NH]
static const size_t OFF_HB  = OFF_WTO + (size_t)ND * NH * 2;       // bf16 hb [NTOK][NH] (permuted rows)
static const size_t WS_NEED = OFF_HB  + (size_t)NTOK * NH * 2;

#define GLDS16(src, dst) __builtin_amdgcn_global_load_lds( \
    (__attribute__((address_space(1))) void*)(void*)(src), \
    (__attribute__((address_space(3))) void*)(dst), 16, 0, 0)

// ---------------- prep kernels ----------------

// fused routing: histogram + prefix + scatter, ONE block (1024 thr)
__global__ void k_route(const int* __restrict__ assign, int* __restrict__ meta) {
    __shared__ int cnt[NE];
    __shared__ int offs_s[NE];
    int tid = threadIdx.x;
    if (tid < NE) cnt[tid] = 0;
    __syncthreads();
    for (int t = tid; t < NTOK; t += 1024) atomicAdd(&cnt[assign[t] & 7], 1);
    __syncthreads();
    if (tid == 0) {
        int o = 0;
        for (int e = 0; e < NE; e++) {
            meta[e] = cnt[e]; meta[16 + e] = o; offs_s[e] = o; o += cnt[e];
        }
    }
    __syncthreads();
    if (tid < NE) cnt[tid] = offs_s[tid];   // reuse as cursors
    __syncthreads();
    int* perm = meta + 512;
    for (int t = tid; t < NTOK; t += 1024) {
        int e = assign[t] & 7;
        int p = atomicAdd(&cnt[e], 1);
        perm[p] = t;
    }
}

// both weight transposes in ONE launch: in [*][R][C] f32 -> out [*][C][R] bf16
__global__ void k_transpose_all(const float* __restrict__ W_e, const float* __restrict__ W_out,
                                bf16* __restrict__ wte, bf16* __restrict__ wto) {
    __shared__ float tile[32][33];
    int b = blockIdx.x;
    const float* in; bf16* outp; int R, C, c0, r0;
    if (b < 8 * 128 * 32) {          // W_e[z]: R=ND(1024), C=NH(4096)
        int z = b >> 12, idx = b & 4095;
        int bx = idx & 127, by = idx >> 7;
        in = W_e + (size_t)z * ND * NH; outp = wte + (size_t)z * NH * ND;
        R = ND; C = NH; c0 = bx * 32; r0 = by * 32;
    } else {                          // W_out: R=NH(4096), C=ND(1024)
        int idx = b - 32768;
        int bx = idx & 31, by = idx >> 5;
        in = W_out; outp = wto;
        R = NH; C = ND; c0 = bx * 32; r0 = by * 32;
    }
    int tx = threadIdx.x & 31, ty = threadIdx.x >> 5;
#pragma unroll
    for (int i = 0; i < 4; i++) {
        int r = r0 + ty + i * 8;
        tile[ty + i * 8][tx] = in[(size_t)r * C + c0 + tx];
    }
    __syncthreads();
#pragma unroll
    for (int i = 0; i < 4; i++) {
        int c = c0 + ty + i * 8;
        outp[(size_t)c * R + r0 + tx] = (bf16)tile[tx][ty + i * 8];
    }
}

// =====================================================================
// Shared GEMM building blocks (256x256, BK=64, 8 waves 2Mx4N).
// Fragment reads: slot s of row r holds granule s^(r&7) (conflict-free).
// =====================================================================

#define BAR { __builtin_amdgcn_s_barrier(); asm volatile("" ::: "memory"); }
#define LGKM0 asm volatile("s_waitcnt lgkmcnt(0)" ::: "memory")
#define VMC8 asm volatile("s_waitcnt vmcnt(8)" ::: "memory")
#define VMC0 asm volatile("s_waitcnt vmcnt(0)" ::: "memory")

#define MFMA_Q(msub, nsub) { \
  __builtin_amdgcn_s_setprio(1); \
  _Pragma("unroll") for (int m = 0; m < 4; m++) \
  _Pragma("unroll") for (int n = 0; n < 2; n++) \
  _Pragma("unroll") for (int k = 0; k < 2; k++) \
    acc[(msub)*4+m][(nsub)*2+n] = __builtin_amdgcn_mfma_f32_16x16x32_bf16( \
        af[m][k], bfr[(nsub)*2+n][k], acc[(msub)*4+m][(nsub)*2+n], 0, 0, 0); \
  __builtin_amdgcn_s_setprio(0); }

// =====================================================================
// GEMM1: h = relu(gather(x) @ W_e[e] + b_e[e]).
// A reg-staged from f32 x (perm lookup + cvt), 2-deep LDS [0,64K).
// B gload_lds from wte, 2-deep LDS [64K,128K), staged at t+2.
// Phases: p0{ldA0,ldB0 | issue A-f32(t+1)} p1{ldB1} p2{ldA1 | gldB0(t+2)}
//         p3{gldB1(t+2) | cvt+ds_write A(t+1) | lgkm0}
// B-landing guarantee: A_WRITE's compiler vmcnt (av older than all pending
// B gloads) transitively drains B(t) before its p0 reads.
// =====================================================================

#define G1_LDA(msub) { \
  const char* Ab = sm + ((i) & 1) * 32768 + wr * 16384; \
  _Pragma("unroll") for (int m = 0; m < 4; m++) { \
    int row = ((msub) * 4 + m) * 16 + lr; \
    af[m][0] = *(const bf16x8*)(Ab + row * 128 + xk0); \
    af[m][1] = *(const bf16x8*)(Ab + row * 128 + xk1); \
  } }

#define G1_LDB(nsub) { \
  const char* Bb = sm + 65536 + ((i) & 1) * 32768 + (wc >> 1) * 16384; \
  _Pragma("unroll") for (int n = 0; n < 2; n++) { \
    int row = (wc & 1) * 64 + ((nsub) * 2 + n) * 16 + lr; \
    bfr[(nsub)*2+n][0] = *(const bf16x8*)(Bb + row * 128 + xk0); \
    bfr[(nsub)*2+n][1] = *(const bf16x8*)(Bb + row * 128 + xk1); \
  } }

#define G1_ALOAD(t) { \
  _Pragma("unroll") for (int h2 = 0; h2 < 2; h2++) \
  _Pragma("unroll") for (int r2 = 0; r2 < 2; r2++) { \
    const float4* s4 = (const float4*)(pax[h2][r2] + (size_t)(t) * 64); \
    av[h2][r2][0] = s4[0]; av[h2][r2][1] = s4[1]; } }

#define G1_AWRITE(t) { \
  char* base = sm + ((t) & 1) * 32768; \
  _Pragma("unroll") for (int h2 = 0; h2 < 2; h2++) \
  _Pragma("unroll") for (int r2 = 0; r2 < 2; r2++) { \
    float4 v0 = av[h2][r2][0], v1 = av[h2][r2][1]; \
    bf16x8 o; \
    o[0] = (bf16)v0.x; o[1] = (bf16)v0.y; o[2] = (bf16)v0.z; o[3] = (bf16)v0.w; \
    o[4] = (bf16)v1.x; o[5] = (bf16)v1.y; o[6] = (bf16)v1.z; o[7] = (bf16)v1.w; \
    *(bf16x8*)(base + h2 * 16384 + (r2 * 64 + sr) * 128 + wslot) = o; } }

#define G1_STAGE_B(t, h) { \
    char* d = sm + 65536 + ((t) & 1) * 32768 + (h) * 16384 + wid * 1024; \
    GLDS16(pb0 + ((h) * 128) * (size_t)ND + (size_t)(t) * 64, d); \
    GLDS16(pb0 + ((h) * 128 + 64) * (size_t)ND + (size_t)(t) * 64, d + 8192); }

__launch_bounds__(512, 2)
__global__ void k_gemm1(const float* __restrict__ x, const bf16* __restrict__ wte,
                        const float* __restrict__ b_e, bf16* __restrict__ hb,
                        const int* __restrict__ meta) {
    __shared__ __align__(16) char sm[131072];
    // expert == XCD (f&7); j fastest within XCD (R6 verified FETCH-optimal)
    int f = blockIdx.x;
    int e = f & 7, q = f >> 3;
    int jj = q % 9, bx = q / 9;
    int cnt = meta[e];
    int rs  = meta[16 + e] + jj * 256;
    int rc  = cnt - jj * 256; if (rc > 256) rc = 256;
    if (rc <= 0) return;
    int n0 = bx * 256;
    const int* perm = meta + 512;

    int tid = threadIdx.x;
    int lane = tid & 63, wid = tid >> 6;
    int wr = wid >> 2, wc = wid & 3;
    int lr = lane & 15, kg = lane >> 4;
    int xk0 = (kg ^ (lr & 7)) * 16;
    int xk1 = ((4 + kg) ^ (lr & 7)) * 16;

    // staging coords: thread covers row sr (in 64-row segment), granule sl
    int sr = tid >> 3, sl = tid & 7;
    int wslot = (sl ^ (sr & 7)) * 16;            // swizzled LDS write slot
    const float* pax[2][2];
#pragma unroll
    for (int h = 0; h < 2; h++)
#pragma unroll
        for (int rr = 0; rr < 2; rr++) {
            int arow = h * 128 + rr * 64 + sr;
            int p = rs + (arow < rc - 1 ? arow : rc - 1);
            pax[h][rr] = x + (size_t)perm[p] * ND + sl * 8;   // f32, natural granule
        }
    // B staged with inverse-swizzled global granule (linear LDS dest)
    int g = sl ^ (sr & 7);
    const bf16* pb0 = wte + ((size_t)e * NH + n0 + sr) * ND + g * 8;

    f32x4 acc[8][4] = {};
    bf16x8 af[4][2], bfr[4][2];
    float4 av[2][2][2];
    const int NT = ND / 64;   // 16

    // prologue
    G1_ALOAD(0);
    G1_STAGE_B(0, 0); G1_STAGE_B(0, 1);
    G1_STAGE_B(1, 0); G1_STAGE_B(1, 1);
    G1_AWRITE(0);            // compiler inserts vmcnt for av(0)
    G1_ALOAD(1);
    G1_AWRITE(1);
    LGKM0;
    VMC0;
    BAR;

#pragma unroll 2
    for (int i = 0; i < NT; i++) {
        G1_LDA(0); G1_LDB(0); if (i + 1 < NT) G1_ALOAD(i + 1);
        BAR; MFMA_Q(0,0); BAR;
        G1_LDB(1);
        BAR; MFMA_Q(0,1); BAR;
        G1_LDA(1); if (i + 2 < NT) { G1_STAGE_B(i + 2, 0); }
        BAR; MFMA_Q(1,0); BAR;
        if (i + 2 < NT) { G1_STAGE_B(i + 2, 1); }
        if (i + 1 < NT) { G1_AWRITE(i + 1); LGKM0; }
        BAR; MFMA_Q(1,1); BAR;
    }

    // epilogue: bias + relu, bf16, permuted (dense) row order
    float bias[4];
#pragma unroll
    for (int n = 0; n < 4; n++) bias[n] = b_e[e * NH + n0 + wc * 64 + n * 16 + lr];
#pragma unroll
    for (int m = 0; m < 8; m++) {
#pragma unroll
        for (int rr = 0; rr < 4; rr++) {
            int row = wr * 128 + m * 16 + kg * 4 + rr;
            if (row < rc) {
                bf16* hp = hb + (size_t)(rs + row) * NH + n0 + wc * 64;
#pragma unroll
                for (int n = 0; n < 4; n++)
                    hp[n * 16 + lr] = (bf16)fmaxf(acc[m][n][rr] + bias[n], 0.0f);
            }
        }
    }
}

// =====================================================================
// GEMM2 (R6-validated, unchanged): A 3-deep / B 2-deep ring, vmcnt(8).
// LDS 160KB: A [0,96K) = 3 x 32K; B [96K,160K) = 2 x 32K.
// =====================================================================

#define LDA2(msub) { \
  const char* Ab = sm + abuf + wr * 16384; \
  _Pragma("unroll") for (int m = 0; m < 4; m++) { \
    int row = ((msub) * 4 + m) * 16 + lr; \
    af[m][0] = *(const bf16x8*)(Ab + row * 128 + xk0); \
    af[m][1] = *(const bf16x8*)(Ab + row * 128 + xk1); \
  } }

#define LDB2(nsub) { \
  const char* Bb = sm + bbuf + (wc >> 1) * 16384; \
  _Pragma("unroll") for (int n = 0; n < 2; n++) { \
    int row = (wc & 1) * 64 + ((nsub) * 2 + n) * 16 + lr; \
    bfr[(nsub)*2+n][0] = *(const bf16x8*)(Bb + row * 128 + xk0); \
    bfr[(nsub)*2+n][1] = *(const bf16x8*)(Bb + row * 128 + xk1); \
  } }

#define DO_TILE2(i, S0, S1, S2, S3, VW) { \
  const int abuf = ((i) % 3) * 32768; \
  const int bbuf = 98304 + ((i) & 1) * 32768; \
  LDA2(0); LDB2(0); S0; BAR; MFMA_Q(0,0); BAR; \
  LDB2(1);          S1; BAR; MFMA_Q(0,1); BAR; \
  LDA2(1);          S2; BAR; MFMA_Q(1,0); BAR; \
                    S3; VW; BAR; MFMA_Q(1,1); BAR; \
}

#define STAGE_A2(t, h) { \
    char* d = sm + ((t) % 3) * 32768 + (h) * 16384 + wid * 1024; \
    GLDS16(pa0 + ((h) * 128) * (size_t)NH + (size_t)(t) * 64, d); \
    GLDS16(pa0 + ((h) * 128 + 64) * (size_t)NH + (size_t)(t) * 64, d + 8192); }
#define STAGE_B2(t, h) { \
    char* d = sm + 98304 + ((t) & 1) * 32768 + (h) * 16384 + wid * 1024; \
    GLDS16(pb0 + ((h) * 128) * (size_t)NH + (size_t)(t) * 64, d); \
    GLDS16(pb0 + ((h) * 128 + 64) * (size_t)NH + (size_t)(t) * 64, d + 8192); }

__launch_bounds__(512, 2)
__global__ void k_gemm2(const bf16* __restrict__ hb, const bf16* __restrict__ wto,
                        const float* __restrict__ b_out, const int* __restrict__ meta,
                        float* __restrict__ out) {
    __shared__ __align__(16) char sm[163840];
    int lin = blockIdx.x;
    int swz = (lin & 7) * 32 + (lin >> 3);   // bijective XCD swizzle, 256 blocks
    int bx = swz & 3, by = swz >> 2;
    int m0 = by * 256, n0 = bx * 256;
    const int* perm = meta + 512;

    int tid = threadIdx.x;
    int lane = tid & 63, wid = tid >> 6;
    int wr = wid >> 2, wc = wid & 3;
    int lr = lane & 15, kg = lane >> 4;
    int xk0 = (kg ^ (lr & 7)) * 16;
    int xk1 = ((4 + kg) ^ (lr & 7)) * 16;

    int sr = tid >> 3, sl = tid & 7;
    int g = sl ^ (sr & 7);
    const bf16* pa0 = hb  + ((size_t)m0 + sr) * NH + g * 8;
    const bf16* pb0 = wto + ((size_t)n0 + sr) * NH + g * 8;

    f32x4 acc[8][4] = {};
    bf16x8 af[4][2], bfr[4][2];
    const int NT = NH / 64;   // 64

    STAGE_A2(0, 0); STAGE_A2(0, 1); STAGE_B2(0, 0); STAGE_B2(0, 1);
    STAGE_A2(1, 0); STAGE_A2(1, 1); STAGE_B2(1, 0); STAGE_B2(1, 1);
    VMC8;
    BAR;

#pragma unroll 6
    for (int i = 0; i < NT - 2; i++)
        DO_TILE2(i, STAGE_A2(i + 2, 0), STAGE_A2(i + 2, 1),
                    STAGE_B2(i + 2, 0), STAGE_B2(i + 2, 1), VMC8);
    DO_TILE2(NT - 2, , , , , VMC0);
    DO_TILE2(NT - 1, , , , , );

    // epilogue: bias, scatter rows to token order via perm
    float bias[4];
#pragma unroll
    for (int n = 0; n < 4; n++) bias[n] = b_out[n0 + wc * 64 + n * 16 + lr];
#pragma unroll
    for (int m = 0; m < 8; m++) {
#pragma unroll
        for (int rr = 0; rr < 4; rr++) {
            int prow = m0 + wr * 128 + m * 16 + kg * 4 + rr;
            int tok = perm[prow];
            float* op = out + (size_t)tok * ND + n0 + wc * 64;
#pragma unroll
            for (int n = 0; n < 4; n++)
                op[n * 16 + lr] = acc[m][n][rr] + bias[n];
        }
    }
}

extern "C" void kernel_launch(void* const* d_in, const int* in_sizes, int n_in,
                              void* d_out, int out_size, void* d_ws, size_t ws_size,
                              hipStream_t stream) {
    const float* x     = (const float*)d_in[0];
    const float* W_e   = (const float*)d_in[1];
    const float* b_e   = (const float*)d_in[2];
    const float* W_out = (const float*)d_in[3];
    const float* b_out = (const float*)d_in[4];
    const int*   assign = (const int*)d_in[5];
    float* out = (float*)d_out;

    if (ws_size < WS_NEED) return;

    char* ws = (char*)d_ws;
    int*  meta = (int*)ws;
    bf16* wte = (bf16*)(ws + OFF_WTE);
    bf16* wto = (bf16*)(ws + OFF_WTO);
    bf16* hb  = (bf16*)(ws + OFF_HB);

    k_route<<<1, 1024, 0, stream>>>(assign, meta);
    k_transpose_all<<<36864, 256, 0, stream>>>(W_e, W_out, wte, wto);
    // grouped GEMM1 (A reg-staged from f32 x directly; no gather pre-pass)
    k_gemm1<<<1152, 512, 0, stream>>>(x, wte, b_e, hb, meta);
    // dense GEMM2 over permuted hb rows, scatter at the end
    k_gemm2<<<256, 512, 0, stream>>>(hb, wto, b_out, meta, out);
}

// Round 10
// 512.928 us; speedup vs baseline: 1.0275x; 1.0275x over previous
//
#include <hip/hip_runtime.h>
#include <hip/hip_bf16.h>
#include <stdint.h>

// Problem dims (fixed)
#define NB 8
#define NS 2048
#define ND 1024
#define NH 4096
#define NE 8
#define NTOK (NB*NS)   // 16384 tokens

typedef __bf16 bf16;
typedef bf16 bf16x8 __attribute__((ext_vector_type(8)));
typedef float f32x4 __attribute__((ext_vector_type(4)));

// ws layout: meta[512] ints + perm[16384] at meta+512, then:
static const size_t OFF_XB  = 128 * 1024;                          // bf16 xbp[NTOK][ND] (PERMUTED rows)
static const size_t OFF_WTE = OFF_XB  + (size_t)NTOK * ND * 2;     // bf16 wte[NE][NH][ND]
static const size_t OFF_WTO = OFF_WTE + (size_t)NE * NH * ND * 2;  // bf16 wto[ND][NH]
static const size_t OFF_HB  = OFF_WTO + (size_t)ND * NH * 2;       // bf16 hb [NTOK][NH] (permuted rows)
static const size_t WS_NEED = OFF_HB  + (size_t)NTOK * NH * 2;

#define GLDS16(src, dst) __builtin_amdgcn_global_load_lds( \
    (__attribute__((address_space(1))) void*)(void*)(src), \
    (__attribute__((address_space(3))) void*)(dst), 16, 0, 0)

// ---------------- prep kernels (R6-validated) ----------------

__global__ void k_route(const int* __restrict__ assign, int* __restrict__ meta) {
    __shared__ int cnt[NE];
    __shared__ int offs_s[NE];
    int tid = threadIdx.x;
    if (tid < NE) cnt[tid] = 0;
    __syncthreads();
    for (int t = tid; t < NTOK; t += 1024) atomicAdd(&cnt[assign[t] & 7], 1);
    __syncthreads();
    if (tid == 0) {
        int o = 0;
        for (int e = 0; e < NE; e++) {
            meta[e] = cnt[e]; meta[16 + e] = o; offs_s[e] = o; o += cnt[e];
        }
    }
    __syncthreads();
    if (tid < NE) cnt[tid] = offs_s[tid];
    __syncthreads();
    int* perm = meta + 512;
    for (int t = tid; t < NTOK; t += 1024) {
        int e = assign[t] & 7;
        int p = atomicAdd(&cnt[e], 1);
        perm[p] = t;
    }
}

__global__ void k_gather_cvt(const float* __restrict__ x, const int* __restrict__ meta,
                             bf16* __restrict__ xbp) {
    long i = (long)blockIdx.x * blockDim.x + threadIdx.x;   // 8 elems each
    int row = (int)(i >> 7);
    int c8  = (int)(i & 127);
    const int* perm = meta + 512;
    int tok = perm[row];
    const float4* s = (const float4*)(x + (size_t)tok * ND + c8 * 8);
    float4 v0 = s[0], v1 = s[1];
    bf16x8 o;
    o[0] = (bf16)v0.x; o[1] = (bf16)v0.y; o[2] = (bf16)v0.z; o[3] = (bf16)v0.w;
    o[4] = (bf16)v1.x; o[5] = (bf16)v1.y; o[6] = (bf16)v1.z; o[7] = (bf16)v1.w;
    *(bf16x8*)(xbp + i * 8) = o;
}

// both weight transposes in ONE launch
__global__ void k_transpose_all(const float* __restrict__ W_e, const float* __restrict__ W_out,
                                bf16* __restrict__ wte, bf16* __restrict__ wto) {
    __shared__ float tile[32][33];
    int b = blockIdx.x;
    const float* in; bf16* outp; int R, C, c0, r0;
    if (b < 32768) {                 // W_e[z]: R=ND, C=NH
        int z = b >> 12, idx = b & 4095;
        int bx = idx & 127, by = idx >> 7;
        in = W_e + (size_t)z * ND * NH; outp = wte + (size_t)z * NH * ND;
        R = ND; C = NH; c0 = bx * 32; r0 = by * 32;
    } else {                          // W_out: R=NH, C=ND
        int idx = b - 32768;
        int bx = idx & 31, by = idx >> 5;
        in = W_out; outp = wto;
        R = NH; C = ND; c0 = bx * 32; r0 = by * 32;
    }
    int tx = threadIdx.x & 31, ty = threadIdx.x >> 5;
#pragma unroll
    for (int i = 0; i < 4; i++) {
        int r = r0 + ty + i * 8;
        tile[ty + i * 8][tx] = in[(size_t)r * C + c0 + tx];
    }
    __syncthreads();
#pragma unroll
    for (int i = 0; i < 4; i++) {
        int c = c0 + ty + i * 8;
        outp[(size_t)c * R + r0 + tx] = (bf16)tile[tx][ty + i * 8];
    }
}

// =====================================================================
// 16-wave GEMM core: 1024 thr (4m x 4n waves), 256x256 tile, BK=64,
// per-wave 64x64 output (acc 4x4xf32x4 = 64 VGPR -> 16 waves/CU).
// LDS 160KB: A 2-deep [0,64K) (stage t+1), B 3-deep [64K,160K) (stage t+2).
// One barrier per K-tile, vmcnt(2) counted (only B(t+2) in flight).
// Operand buf = 256 rows x 64k bf16 (128B row); slot s of row r holds
// granule s^(r&7) (verified conflict-free XOR swizzle).
// Staging: thread covers row h*128+(tid>>3), slot tid&7, source granule
// (tid&7)^((tid>>3)&7); dest = base + h*16K + tid*16 (wave-uniform+lane*16).
// =====================================================================

#define BAR { __builtin_amdgcn_s_barrier(); asm volatile("" ::: "memory"); }
#define VMC2 asm volatile("s_waitcnt vmcnt(2)" ::: "memory")
#define VMC0 asm volatile("s_waitcnt vmcnt(0)" ::: "memory")
#define SCB  __builtin_amdgcn_sched_barrier(0)

#define FRAGS(xk) { \
  _Pragma("unroll") for (int m = 0; m < 4; m++) \
    af[m] = *(const bf16x8*)(Ab + (wm * 64 + m * 16 + lr) * 128 + (xk)); \
  _Pragma("unroll") for (int n = 0; n < 4; n++) \
    bf[n] = *(const bf16x8*)(Bb + (wn * 64 + n * 16 + lr) * 128 + (xk)); }

#define MF16 { \
  __builtin_amdgcn_s_setprio(1); \
  _Pragma("unroll") for (int m = 0; m < 4; m++) \
  _Pragma("unroll") for (int n = 0; n < 4; n++) \
    acc[m][n] = __builtin_amdgcn_mfma_f32_16x16x32_bf16(af[m], bf[n], acc[m][n], 0, 0, 0); \
  __builtin_amdgcn_s_setprio(0); }

// stage one 32KB operand buffer (2 gload_lds/thread)
#define STAGE_OP(baseoff, bufidx, p0, p1, koff) { \
    char* d = sm + (baseoff) + (bufidx) * 32768 + tid * 16; \
    GLDS16((p0) + (koff), d); \
    GLDS16((p1) + (koff), d + 16384); }

#define KSTEP(t, NT) { \
  const char* Ab = sm + ((t) & 1) * 32768; \
  const char* Bb = sm + 65536 + ((t) % 3) * 32768; \
  bf16x8 af[4], bf[4]; \
  FRAGS(xk0); \
  if ((t) + 1 < (NT)) STAGE_OP(0, ((t) + 1) & 1, pa0, pa1, (size_t)((t) + 1) * 64); \
  SCB; MF16; SCB; \
  FRAGS(xk1); \
  if ((t) + 2 < (NT)) STAGE_OP(65536, ((t) + 2) % 3, pb0, pb1, (size_t)((t) + 2) * 64); \
  SCB; MF16; \
  if ((t) + 2 < (NT)) { VMC2; } else { VMC0; } \
  BAR; \
}

__launch_bounds__(1024, 4)
__global__ void k_gemm1(const bf16* __restrict__ xbp, const bf16* __restrict__ wte,
                        const float* __restrict__ b_e, bf16* __restrict__ hb,
                        const int* __restrict__ meta) {
    __shared__ __align__(16) char sm[163840];
    // expert == XCD (f&7); j fastest within XCD (R6 verified FETCH-optimal)
    int f = blockIdx.x;
    int e = f & 7, q = f >> 3;
    int jj = q % 9, bx = q / 9;
    int cnt = meta[e];
    int rs  = meta[16 + e] + jj * 256;
    int rc  = cnt - jj * 256; if (rc > 256) rc = 256;
    if (rc <= 0) return;
    int n0 = bx * 256;

    int tid = threadIdx.x;
    int lane = tid & 63, wid = tid >> 6;
    int wm = wid >> 2, wn = wid & 3;
    int lr = lane & 15, kg = lane >> 4;
    int xk0 = ((kg)     ^ (lr & 7)) * 16;
    int xk1 = ((4 + kg) ^ (lr & 7)) * 16;

    // staging coords
    int srow = tid >> 3;
    int g = (tid & 7) ^ (srow & 7);
    int r0 = rs + (srow < rc - 1 ? srow : rc - 1);
    int r1 = rs + (128 + srow < rc - 1 ? 128 + srow : rc - 1);
    const bf16* pa0 = xbp + (size_t)r0 * ND + g * 8;
    const bf16* pa1 = xbp + (size_t)r1 * ND + g * 8;
    const bf16* pb0 = wte + ((size_t)e * NH + n0 + srow) * ND + g * 8;
    const bf16* pb1 = pb0 + (size_t)128 * ND;

    f32x4 acc[4][4] = {};
    const int NT = ND / 64;   // 16

    // prologue: A(0), B(0), B(1); wait A0+B0 (vmcnt(2) leaves B1 in flight)
    STAGE_OP(0, 0, pa0, pa1, 0);
    STAGE_OP(65536, 0, pb0, pb1, 0);
    STAGE_OP(65536, 1, pb0, pb1, 64);
    VMC2;
    BAR;

#pragma unroll 2
    for (int t = 0; t < NT; ++t) KSTEP(t, NT);

    // epilogue: bias + relu, bf16, permuted (dense) row order
    float bias[4];
#pragma unroll
    for (int n = 0; n < 4; n++) bias[n] = b_e[e * NH + n0 + wn * 64 + n * 16 + lr];
#pragma unroll
    for (int m = 0; m < 4; m++) {
#pragma unroll
        for (int rr = 0; rr < 4; rr++) {
            int row = wm * 64 + m * 16 + kg * 4 + rr;
            if (row < rc) {
                bf16* hp = hb + (size_t)(rs + row) * NH + n0 + wn * 64;
#pragma unroll
                for (int n = 0; n < 4; n++)
                    hp[n * 16 + lr] = (bf16)fmaxf(acc[m][n][rr] + bias[n], 0.0f);
            }
        }
    }
}

__launch_bounds__(1024, 4)
__global__ void k_gemm2(const bf16* __restrict__ hb, const bf16* __restrict__ wto,
                        const float* __restrict__ b_out, const int* __restrict__ meta,
                        float* __restrict__ out) {
    __shared__ __align__(16) char sm[163840];
    int lin = blockIdx.x;
    int swz = (lin & 7) * 32 + (lin >> 3);   // bijective XCD swizzle, 256 blocks
    int bxn = swz & 3, by = swz >> 2;
    int m0 = by * 256, n0 = bxn * 256;
    const int* perm = meta + 512;

    int tid = threadIdx.x;
    int lane = tid & 63, wid = tid >> 6;
    int wm = wid >> 2, wn = wid & 3;
    int lr = lane & 15, kg = lane >> 4;
    int xk0 = ((kg)     ^ (lr & 7)) * 16;
    int xk1 = ((4 + kg) ^ (lr & 7)) * 16;

    int srow = tid >> 3;
    int g = (tid & 7) ^ (srow & 7);
    const bf16* pa0 = hb  + ((size_t)m0 + srow) * NH + g * 8;
    const bf16* pa1 = pa0 + (size_t)128 * NH;
    const bf16* pb0 = wto + ((size_t)n0 + srow) * NH + g * 8;
    const bf16* pb1 = pb0 + (size_t)128 * NH;

    f32x4 acc[4][4] = {};
    const int NT = NH / 64;   // 64

    STAGE_OP(0, 0, pa0, pa1, 0);
    STAGE_OP(65536, 0, pb0, pb1, 0);
    STAGE_OP(65536, 1, pb0, pb1, 64);
    VMC2;
    BAR;

#pragma unroll 2
    for (int t = 0; t < NT; ++t) KSTEP(t, NT);

    // epilogue: bias, scatter rows to token order via perm
    float bias[4];
#pragma unroll
    for (int n = 0; n < 4; n++) bias[n] = b_out[n0 + wn * 64 + n * 16 + lr];
#pragma unroll
    for (int m = 0; m < 4; m++) {
#pragma unroll
        for (int rr = 0; rr < 4; rr++) {
            int prow = m0 + wm * 64 + m * 16 + kg * 4 + rr;
            int tok = perm[prow];
            float* op = out + (size_t)tok * ND + n0 + wn * 64;
#pragma unroll
            for (int n = 0; n < 4; n++)
                op[n * 16 + lr] = acc[m][n][rr] + bias[n];
        }
    }
}

extern "C" void kernel_launch(void* const* d_in, const int* in_sizes, int n_in,
                              void* d_out, int out_size, void* d_ws, size_t ws_size,
                              hipStream_t stream) {
    const float* x     = (const float*)d_in[0];
    const float* W_e   = (const float*)d_in[1];
    const float* b_e   = (const float*)d_in[2];
    const float* W_out = (const float*)d_in[3];
    const float* b_out = (const float*)d_in[4];
    const int*   assign = (const int*)d_in[5];
    float* out = (float*)d_out;

    if (ws_size < WS_NEED) return;

    char* ws = (char*)d_ws;
    int*  meta = (int*)ws;
    bf16* xbp = (bf16*)(ws + OFF_XB);
    bf16* wte = (bf16*)(ws + OFF_WTE);
    bf16* wto = (bf16*)(ws + OFF_WTO);
    bf16* hb  = (bf16*)(ws + OFF_HB);

    k_route<<<1, 1024, 0, stream>>>(assign, meta);
    k_gather_cvt<<<NTOK * ND / (256 * 8), 256, 0, stream>>>(x, meta, xbp);
    k_transpose_all<<<36864, 256, 0, stream>>>(W_e, W_out, wte, wto);
    // grouped GEMM1: 8 experts (==XCD) x (9 j fastest x 16 bx), 16-wave blocks
    k_gemm1<<<1152, 1024, 0, stream>>>(xbp, wte, b_e, hb, meta);
    // dense GEMM2 over permuted hb rows, scatter at the end
    k_gemm2<<<256, 1024, 0, stream>>>(hb, wto, b_out, meta, out);
}

// Round 11
// 412.716 us; speedup vs baseline: 1.2770x; 1.2428x over previous
//
#include <hip/hip_runtime.h>
#include <hip/hip_bf16.h>
#include <stdint.h>

// Problem dims (fixed)
#define NB 8
#define NS 2048
#define ND 1024
#define NH 4096
#define NE 8
#define NTOK (NB*NS)   // 16384 tokens

typedef __bf16 bf16;
typedef bf16 bf16x8 __attribute__((ext_vector_type(8)));
typedef float f32x4 __attribute__((ext_vector_type(4)));

// ws layout: meta[512] ints + perm[16384] at meta+512, then:
static const size_t OFF_XB  = 128 * 1024;                          // bf16 xb [NTOK][ND]  (token order)
static const size_t OFF_WTE = OFF_XB  + (size_t)NTOK * ND * 2;     // bf16 wte[NE][NH][ND]
static const size_t OFF_WTO = OFF_WTE + (size_t)NE * NH * ND * 2;  // bf16 wto[ND][NH]
static const size_t OFF_HB  = OFF_WTO + (size_t)ND * NH * 2;       // bf16 hb [NTOK][NH] (permuted rows)
static const size_t WS_NEED = OFF_HB  + (size_t)NTOK * NH * 2;

#define GLDS16(src, dst) __builtin_amdgcn_global_load_lds( \
    (__attribute__((address_space(1))) void*)(void*)(src), \
    (__attribute__((address_space(3))) void*)(dst), 16, 0, 0)

// =====================================================================
// ONE prep kernel: block 0 = routing; blocks [1,8192] = x f32->bf16 cvt;
// blocks [8193,45056] = weight transposes.  All independent; overlap on
// the machine; deletes 2 launch gaps + the separate gather pass.
// =====================================================================
__global__ void k_prep(const int* __restrict__ assign, const float* __restrict__ x,
                       const float* __restrict__ W_e, const float* __restrict__ W_out,
                       int* __restrict__ meta, bf16* __restrict__ xb,
                       bf16* __restrict__ wte, bf16* __restrict__ wto) {
    int b = blockIdx.x;
    int tid = threadIdx.x;
    if (b == 0) {
        // ---- routing: histogram + prefix + scatter (256 thr) ----
        __shared__ int cnt[NE], cur[NE];
        if (tid < NE) cnt[tid] = 0;
        __syncthreads();
        for (int t = tid; t < NTOK; t += 256) atomicAdd(&cnt[assign[t] & 7], 1);
        __syncthreads();
        if (tid == 0) {
            int o = 0;
            for (int e = 0; e < NE; e++) {
                meta[e] = cnt[e]; meta[16 + e] = o; cur[e] = o; o += cnt[e];
            }
        }
        __syncthreads();
        int* perm = meta + 512;
        for (int t = tid; t < NTOK; t += 256) {
            int e = assign[t] & 7;
            int p = atomicAdd(&cur[e], 1);
            perm[p] = t;
        }
        return;
    }
    if (b <= 8192) {
        // ---- x cvt: 8 elems/thread, token order ----
        long i = (long)(b - 1) * 256 + tid;
        const float4* s = (const float4*)(x + i * 8);
        float4 v0 = s[0], v1 = s[1];
        bf16x8 o;
        o[0] = (bf16)v0.x; o[1] = (bf16)v0.y; o[2] = (bf16)v0.z; o[3] = (bf16)v0.w;
        o[4] = (bf16)v1.x; o[5] = (bf16)v1.y; o[6] = (bf16)v1.z; o[7] = (bf16)v1.w;
        *(bf16x8*)(xb + i * 8) = o;
        return;
    }
    // ---- weight transpose: in [*][R][C] f32 -> out [*][C][R] bf16 ----
    __shared__ float tile[32][33];
    int idx = b - 8193;
    const float* in; bf16* outp; int R, C, c0, r0;
    if (idx < 32768) {               // W_e[z]: R=ND, C=NH
        int z = idx >> 12, q = idx & 4095;
        int bx = q & 127, by = q >> 7;
        in = W_e + (size_t)z * ND * NH; outp = wte + (size_t)z * NH * ND;
        R = ND; C = NH; c0 = bx * 32; r0 = by * 32;
    } else {                          // W_out: R=NH, C=ND
        int q = idx - 32768;
        int bx = q & 31, by = q >> 5;
        in = W_out; outp = wto;
        R = NH; C = ND; c0 = bx * 32; r0 = by * 32;
    }
    int tx = tid & 31, ty = tid >> 5;
#pragma unroll
    for (int i = 0; i < 4; i++) {
        int r = r0 + ty + i * 8;
        tile[ty + i * 8][tx] = in[(size_t)r * C + c0 + tx];
    }
    __syncthreads();
#pragma unroll
    for (int i = 0; i < 4; i++) {
        int c = c0 + ty + i * 8;
        outp[(size_t)c * R + r0 + tx] = (bf16)tile[tx][ty + i * 8];
    }
}

// =====================================================================
// R6-validated 8-phase 256x256 GEMM core, BK=64, 8 waves (2Mx4N).
// A: 3-deep ring [0,96K) staged t+2; B: 2-deep [96K,160K) staged t+2;
// vmcnt(8) once per K-tile.  Operand region = 128 rows x 64k bf16
// (128B rows); slot s of row r holds granule s^(r&7) (conflict-free).
// =====================================================================

#define BAR { __builtin_amdgcn_s_barrier(); asm volatile("" ::: "memory"); }
#define VMC8 asm volatile("s_waitcnt vmcnt(8)" ::: "memory")
#define VMC0 asm volatile("s_waitcnt vmcnt(0)" ::: "memory")

#define LDA(msub) { \
  const char* Ab = sm + abuf + wr * 16384; \
  _Pragma("unroll") for (int m = 0; m < 4; m++) { \
    int row = ((msub) * 4 + m) * 16 + lr; \
    af[m][0] = *(const bf16x8*)(Ab + row * 128 + xk0); \
    af[m][1] = *(const bf16x8*)(Ab + row * 128 + xk1); \
  } }

#define LDB(nsub) { \
  const char* Bb = sm + bbuf + (wc >> 1) * 16384; \
  _Pragma("unroll") for (int n = 0; n < 2; n++) { \
    int row = (wc & 1) * 64 + ((nsub) * 2 + n) * 16 + lr; \
    bfr[(nsub)*2+n][0] = *(const bf16x8*)(Bb + row * 128 + xk0); \
    bfr[(nsub)*2+n][1] = *(const bf16x8*)(Bb + row * 128 + xk1); \
  } }

#define MFMA_Q(msub, nsub) { \
  __builtin_amdgcn_s_setprio(1); \
  _Pragma("unroll") for (int m = 0; m < 4; m++) \
  _Pragma("unroll") for (int n = 0; n < 2; n++) \
  _Pragma("unroll") for (int k = 0; k < 2; k++) \
    acc[(msub)*4+m][(nsub)*2+n] = __builtin_amdgcn_mfma_f32_16x16x32_bf16( \
        af[m][k], bfr[(nsub)*2+n][k], acc[(msub)*4+m][(nsub)*2+n], 0, 0, 0); \
  __builtin_amdgcn_s_setprio(0); }

#define DO_TILE(i, S0, S1, S2, S3, VW) { \
  const int abuf = ((i) % 3) * 32768; \
  const int bbuf = 98304 + ((i) & 1) * 32768; \
  LDA(0); LDB(0); S0; BAR; MFMA_Q(0,0); BAR; \
  LDB(1);         S1; BAR; MFMA_Q(0,1); BAR; \
  LDA(1);         S2; BAR; MFMA_Q(1,0); BAR; \
                  S3; VW; BAR; MFMA_Q(1,1); BAR; \
}

#define STAGE_A(t, h) { \
    char* d = sm + ((t) % 3) * 32768 + (h) * 16384 + wid * 1024; \
    GLDS16(srcA(t, h, 0), d); \
    GLDS16(srcA(t, h, 1), d + 8192); }
#define STAGE_B(t, h) { \
    char* d = sm + 98304 + ((t) & 1) * 32768 + (h) * 16384 + wid * 1024; \
    GLDS16(srcB(t, h, 0), d); \
    GLDS16(srcB(t, h, 1), d + 8192); }

__launch_bounds__(512, 2)
__global__ void k_gemm1(const bf16* __restrict__ xb, const bf16* __restrict__ wte,
                        const float* __restrict__ b_e, bf16* __restrict__ hb,
                        const int* __restrict__ meta) {
    __shared__ __align__(16) char sm[163840];
    // expert == XCD (f&7); j fastest within XCD (R6 verified FETCH-optimal)
    int f = blockIdx.x;
    int e = f & 7, q = f >> 3;
    int jj = q % 9, bx = q / 9;
    int cnt = meta[e];
    int rs  = meta[16 + e] + jj * 256;
    int rc  = cnt - jj * 256; if (rc > 256) rc = 256;
    if (rc <= 0) return;
    int n0 = bx * 256;
    const int* perm = meta + 512;

    int tid = threadIdx.x;
    int lane = tid & 63, wid = tid >> 6;
    int wr = wid >> 2, wc = wid & 3;
    int lr = lane & 15, kg = lane >> 4;
    int xk0 = (kg ^ (lr & 7)) * 16;
    int xk1 = ((4 + kg) ^ (lr & 7)) * 16;

    int sr = tid >> 3, sl = tid & 7;
    int g = sl ^ (sr & 7);
    const bf16* pa[2][2];
#pragma unroll
    for (int h = 0; h < 2; h++)
#pragma unroll
      for (int rr = 0; rr < 2; rr++) {
        int arow = h * 128 + rr * 64 + sr;
        int p = rs + (arow < rc - 1 ? arow : rc - 1);
        pa[h][rr] = xb + (size_t)perm[p] * ND + g * 8;   // perm-indirect A
      }
    const bf16* pb0 = wte + ((size_t)e * NH + n0 + sr) * ND + g * 8;

#define srcA(t, h, rr) (pa[h][rr] + (size_t)(t) * 64)
#define srcB(t, h, rr) (pb0 + ((h) * 128 + (rr) * 64) * (size_t)ND + (size_t)(t) * 64)

    f32x4 acc[8][4] = {};
    bf16x8 af[4][2], bfr[4][2];
    const int NT = ND / 64;   // 16

    STAGE_A(0, 0); STAGE_A(0, 1); STAGE_B(0, 0); STAGE_B(0, 1);
    STAGE_A(1, 0); STAGE_A(1, 1); STAGE_B(1, 0); STAGE_B(1, 1);
    VMC8;
    BAR;

#pragma unroll 2
    for (int i = 0; i < NT - 2; i++)
        DO_TILE(i, STAGE_A(i + 2, 0), STAGE_A(i + 2, 1),
                   STAGE_B(i + 2, 0), STAGE_B(i + 2, 1), VMC8);
    DO_TILE(NT - 2, , , , , VMC0);
    DO_TILE(NT - 1, , , , , );

    // epilogue: bias + relu, bf16, permuted (dense) row order
    float bias[4];
#pragma unroll
    for (int n = 0; n < 4; n++) bias[n] = b_e[e * NH + n0 + wc * 64 + n * 16 + lr];
#pragma unroll
    for (int m = 0; m < 8; m++) {
#pragma unroll
        for (int rr = 0; rr < 4; rr++) {
            int row = wr * 128 + m * 16 + kg * 4 + rr;
            if (row < rc) {
                bf16* hp = hb + (size_t)(rs + row) * NH + n0 + wc * 64;
#pragma unroll
                for (int n = 0; n < 4; n++)
                    hp[n * 16 + lr] = (bf16)fmaxf(acc[m][n][rr] + bias[n], 0.0f);
            }
        }
    }
#undef srcA
#undef srcB
}

__launch_bounds__(512, 2)
__global__ void k_gemm2(const bf16* __restrict__ hb, const bf16* __restrict__ wto,
                        const float* __restrict__ b_out, const int* __restrict__ meta,
                        float* __restrict__ out) {
    __shared__ __align__(16) char sm[163840];
    int lin = blockIdx.x;
    int swz = (lin & 7) * 32 + (lin >> 3);   // bijective XCD swizzle, 256 blocks
    int bx = swz & 3, by = swz >> 2;
    int m0 = by * 256, n0 = bx * 256;
    const int* perm = meta + 512;

    int tid = threadIdx.x;
    int lane = tid & 63, wid = tid >> 6;
    int wr = wid >> 2, wc = wid & 3;
    int lr = lane & 15, kg = lane >> 4;
    int xk0 = (kg ^ (lr & 7)) * 16;
    int xk1 = ((4 + kg) ^ (lr & 7)) * 16;

    int sr = tid >> 3, sl = tid & 7;
    int g = sl ^ (sr & 7);
    const bf16* pa0 = hb  + ((size_t)m0 + sr) * NH + g * 8;
    const bf16* pb0 = wto + ((size_t)n0 + sr) * NH + g * 8;

#define srcA(t, h, rr) (pa0 + ((h) * 128 + (rr) * 64) * (size_t)NH + (size_t)(t) * 64)
#define srcB(t, h, rr) (pb0 + ((h) * 128 + (rr) * 64) * (size_t)NH + (size_t)(t) * 64)

    f32x4 acc[8][4] = {};
    bf16x8 af[4][2], bfr[4][2];
    const int NT = NH / 64;   // 64

    STAGE_A(0, 0); STAGE_A(0, 1); STAGE_B(0, 0); STAGE_B(0, 1);
    STAGE_A(1, 0); STAGE_A(1, 1); STAGE_B(1, 0); STAGE_B(1, 1);
    VMC8;
    BAR;

#pragma unroll 6
    for (int i = 0; i < NT - 2; i++)
        DO_TILE(i, STAGE_A(i + 2, 0), STAGE_A(i + 2, 1),
                   STAGE_B(i + 2, 0), STAGE_B(i + 2, 1), VMC8);
    DO_TILE(NT - 2, , , , , VMC0);
    DO_TILE(NT - 1, , , , , );

    // epilogue: bias, scatter rows to token order via perm
    float bias[4];
#pragma unroll
    for (int n = 0; n < 4; n++) bias[n] = b_out[n0 + wc * 64 + n * 16 + lr];
#pragma unroll
    for (int m = 0; m < 8; m++) {
#pragma unroll
        for (int rr = 0; rr < 4; rr++) {
            int prow = m0 + wr * 128 + m * 16 + kg * 4 + rr;
            int tok = perm[prow];
            float* op = out + (size_t)tok * ND + n0 + wc * 64;
#pragma unroll
            for (int n = 0; n < 4; n++)
                op[n * 16 + lr] = acc[m][n][rr] + bias[n];
        }
    }
#undef srcA
#undef srcB
}

extern "C" void kernel_launch(void* const* d_in, const int* in_sizes, int n_in,
                              void* d_out, int out_size, void* d_ws, size_t ws_size,
                              hipStream_t stream) {
    const float* x     = (const float*)d_in[0];
    const float* W_e   = (const float*)d_in[1];
    const float* b_e   = (const float*)d_in[2];
    const float* W_out = (const float*)d_in[3];
    const float* b_out = (const float*)d_in[4];
    const int*   assign = (const int*)d_in[5];
    float* out = (float*)d_out;

    if (ws_size < WS_NEED) return;

    char* ws = (char*)d_ws;
    int*  meta = (int*)ws;
    bf16* xb  = (bf16*)(ws + OFF_XB);
    bf16* wte = (bf16*)(ws + OFF_WTE);
    bf16* wto = (bf16*)(ws + OFF_WTO);
    bf16* hb  = (bf16*)(ws + OFF_HB);

    // ONE prep launch: route (1 blk) + x cvt (8192) + both transposes (36864)
    k_prep<<<45057, 256, 0, stream>>>(assign, x, W_e, W_out, meta, xb, wte, wto);
    // grouped GEMM1 (R6 core): 8 experts (==XCD) x (9 j fastest x 16 bx)
    k_gemm1<<<1152, 512, 0, stream>>>(xb, wte, b_e, hb, meta);
    // dense GEMM2 (R6 core) over permuted hb rows, scatter at the end
    k_gemm2<<<256, 512, 0, stream>>>(hb, wto, b_out, meta, out);
}